// Round 4
// baseline (333.293 us; speedup 1.0000x reference)
//
#include <hip/hip_runtime.h>
#include <hip/hip_bf16.h>

// Problem constants
#define T_DIM 2048
#define B_DIM 8
#define D_DIM 1024
#define M_DIM (T_DIM * B_DIM)     // 16384
#define K_DIM D_DIM               // 1024
#define NW_DIM (2 * D_DIM)        // 2048 combined GEMM cols (alpha | v)
#define NCH (B_DIM * D_DIM)       // 8192 channels
#define NCH4 (NCH / 4)            // 2048 float4 channels
#define CHUNKS 256
#define CHUNK_LEN 8               // 256*8 = 2048 = T

typedef __attribute__((ext_vector_type(8))) short bf16x8;
typedef __attribute__((ext_vector_type(4))) float f32x4;

__device__ __forceinline__ unsigned short bf16_rne(float f) {
    unsigned u = __float_as_uint(f);
    unsigned r = u + 0x7fffu + ((u >> 16) & 1u);
    return (unsigned short)(r >> 16);
}

__device__ __forceinline__ float sigmoidf(float z) {
    return 1.0f / (1.0f + __expf(-z));
}

__device__ __forceinline__ void load_lds16(const void* g, void* l) {
    __builtin_amdgcn_global_load_lds(
        (const __attribute__((address_space(1))) void*)g,
        (__attribute__((address_space(3))) void*)l,
        16, 0, 0);
}

// ---------------- fused input conversion: x, Wa, Wv -> bf16 ----------------
__global__ __launch_bounds__(256) void convert_all_kernel(
    const float4* __restrict__ x,
    const float4* __restrict__ Wa,
    const float4* __restrict__ Wv,
    ushort4* __restrict__ xb,
    ushort4* __restrict__ Wcat) {
    const int nx4 = M_DIM * K_DIM / 4;       // 4194304
    const int half4 = D_DIM * D_DIM / 4;     // 262144
    int i = blockIdx.x * 256 + threadIdx.x;
    float4 f;
    ushort4* __restrict__ dst;
    int di;
    if (i < nx4) {
        f = x[i];
        dst = xb;
        di = i;
    } else {
        int j = i - nx4;
        f = (j < half4) ? Wa[j] : Wv[j - half4];
        dst = Wcat;
        di = j;
    }
    ushort4 o;
    o.x = bf16_rne(f.x);
    o.y = bf16_rne(f.y);
    o.z = bf16_rne(f.z);
    o.w = bf16_rne(f.w);
    dst[di] = o;
}

// ---------------- fused bf16 MFMA GEMM, 128x256 tile, 2 blocks/CU --------
// (unchanged from R3 — clean A/B on the scan restructure this round)
// A: [M,K] bf16 row-major.  Wcat: [2048,1024] bf16 row-major (B^T layout).
// cols [0,1024): alpha = sigmoid(xWa^T + ba) -> alpha_dst
// cols [1024,2048): v = xWv^T + bv -> v_dst. Both dsts row stride 1024.
//
//  - wave tile 64x64 (acc=64 regs), combined ~128 => 4 waves/SIMD
//    (__launch_bounds__(512,4)); ring-3 of BK=32 buffers (72 KiB) =>
//    2 blocks/CU. 1024 blocks, bijective XCD swizzle.
//  - Depth-2 prefetch; steady vmcnt(3); ONE barrier per K-tile.
//  - LDS XOR swizzle (verified 0 conflicts); inverse perm on global source.
// Known remaining bottleneck (R3 counters): LDS-read BW — 64 KiB frag reads
// per block-K-tile (A halves read 4x, B quarters 2x). Fix would be the
// 128x64-wave m201 schedule; deferred.
__global__ __launch_bounds__(512, 4) void gemm_fused_kernel(
    const unsigned short* __restrict__ A,
    const unsigned short* __restrict__ W,
    const float* __restrict__ ba,
    const float* __restrict__ bv,
    float* __restrict__ alpha_dst,
    float* __restrict__ v_dst) {
    extern __shared__ __attribute__((aligned(16))) char smem[];  // 3*24576

    const int tid = threadIdx.x;
    const int lane = tid & 63;
    const int w = tid >> 6;          // wave 0..7
    const int wm = w >> 2;           // wave row (0..1) -> 64 rows each
    const int wn = w & 3;            // wave col (0..3) -> 64 cols each
    const int quad = lane >> 4;      // 0..3
    const int l16 = lane & 15;

    const int bid = blockIdx.x;
    const int swz = (bid & 7) * 128 + (bid >> 3);
    const int bx = swz & 7;          // N tile (0..7)
    const int by = swz >> 3;         // M tile (0..127)
    const int bm = by * 128;
    const int bn = bx * 256;         // col in the 2048-wide space

    const int vsw = (((l16 & 1) << 2) | quad) ^ (l16 >> 1);
    const int rdA = wm * 4096 + (l16 >> 1) * 128 + vsw * 16;  // + i*1024
    const int rdB = wn * 4096 + (l16 >> 1) * 128 + vsw * 16;  // + j*1024

    const int hl = lane >> 3;            // 0..7
    const int vp = (lane & 7) ^ hl;
    const int qsrc = vp & 3;
    const int rb = (vp >> 2) & 1;
    const int rA  = 16 * w + 2 * hl + rb;        // A tile row 0..127
    const int rB0 = 32 * w + 2 * hl + rb;        // B tile row (grp 2w)
    const int rB1 = rB0 + 16;                    // B tile row (grp 2w+1)
    const char* Ab = (const char*)A;
    const char* Wb = (const char*)W;
    const size_t offA  = (size_t)(bm + rA ) * 2048 + (size_t)qsrc * 16;
    const size_t offB0 = (size_t)(bn + rB0) * 2048 + (size_t)qsrc * 16;
    const size_t offB1 = (size_t)(bn + rB1) * 2048 + (size_t)qsrc * 16;
    const int ldsA  = w * 1024;          // wave-uniform dests
    const int ldsB0 = (2 * w) * 1024;
    const int ldsB1 = (2 * w + 1) * 1024;

    f32x4 acc[4][4];
    {
        f32x4 zero = {0.f, 0.f, 0.f, 0.f};
#pragma unroll
        for (int i = 0; i < 4; ++i)
#pragma unroll
            for (int j = 0; j < 4; ++j) acc[i][j] = zero;
    }

    auto stage = [&](int buf, int t) {
        char* bA = smem + buf * 24576;
        char* bB = bA + 8192;
        const size_t ko = (size_t)t * 64;
        load_lds16(Ab + offA + ko, bA + ldsA);
        load_lds16(Wb + offB0 + ko, bB + ldsB0);
        load_lds16(Wb + offB1 + ko, bB + ldsB1);
    };

    auto tile_step = [&](int buf, int nbuf, int tn, bool do_stage, int vm,
                         bool bar) {
        const char* bA = smem + buf * 24576;
        const char* bB = bA + 8192;
        bf16x8 af[4], bfr[4];
#pragma unroll
        for (int i = 0; i < 4; ++i)
            af[i] = *(const bf16x8*)(bA + rdA + i * 1024);
#pragma unroll
        for (int j = 0; j < 4; ++j)
            bfr[j] = *(const bf16x8*)(bB + rdB + j * 1024);
        if (do_stage) stage(nbuf, tn);
        asm volatile("s_waitcnt lgkmcnt(0)" ::: "memory");
        __builtin_amdgcn_sched_barrier(0);
        __builtin_amdgcn_s_setprio(1);
#pragma unroll
        for (int i = 0; i < 4; ++i)
#pragma unroll
            for (int j = 0; j < 4; ++j)
                acc[i][j] = __builtin_amdgcn_mfma_f32_16x16x32_bf16(
                    af[i], bfr[j], acc[i][j], 0, 0, 0);
        __builtin_amdgcn_s_setprio(0);
        if (vm == 3) asm volatile("s_waitcnt vmcnt(3)" ::: "memory");
        else if (vm == 0) asm volatile("s_waitcnt vmcnt(0)" ::: "memory");
        if (bar) __builtin_amdgcn_s_barrier();
    };

    stage(0, 0);
    stage(1, 1);
    asm volatile("s_waitcnt vmcnt(3)" ::: "memory");
    __builtin_amdgcn_s_barrier();

    for (int it = 0; it < 10; ++it) {
        const int t = it * 3;
        tile_step(0, 2, t + 2, true, 3, true);
        tile_step(1, 0, t + 3, true, 3, true);
        tile_step(2, 1, t + 4, true, 3, true);
    }
    tile_step(0, 0, 0, false, 0, true);    // tile 30; drain tile 31's loads
    tile_step(1, 0, 0, false, -1, false);  // tile 31; no wait/barrier

    const bool is_alpha = (bn < D_DIM);
    float* __restrict__ dst = is_alpha ? alpha_dst : v_dst;
    const float* __restrict__ bias = is_alpha ? ba : bv;
    const int nb = bn - (is_alpha ? 0 : D_DIM);
#pragma unroll
    for (int j = 0; j < 4; ++j) {
        const int n = nb + wn * 64 + j * 16 + l16;
        const float bias_n = bias[n];
#pragma unroll
        for (int i = 0; i < 4; ++i) {
            const int m0 = bm + wm * 64 + i * 16 + quad * 4;
#pragma unroll
            for (int r = 0; r < 4; ++r) {
                float val = acc[i][j][r] + bias_n;
                if (is_alpha) val = sigmoidf(val);
                dst[(size_t)(m0 + r) * D_DIM + n] = val;
            }
        }
    }
}

// ---------------- chunked parallel scan ----------------
// h_t = a_t*h_{t-1} + (1-a_t)*v_t  == affine h_out = P*h_in + Q per chunk.
// R3 diagnosis: CHUNKS=64 gave only 2048 waves (8/CU, 25% occ) for the two
// big streaming passes -> latency-bound at ~2.5 TB/s. CHUNKS=256/LEN=8
// gives 8192 waves (32/CU) with 8-deep unrolled independent loads.

// Phase 1: per (chunk, channel4) compute chunk composition (P,Q).
__global__ __launch_bounds__(256) void scan_phase1_kernel(
    const float4* __restrict__ alpha,  // [T][NCH4]
    const float4* __restrict__ v,      // [T][NCH4]
    float4* __restrict__ P,            // [CHUNKS][NCH4]
    float4* __restrict__ Q) {
    const int j4 = blockIdx.x * 256 + threadIdx.x;  // 0..NCH4-1
    const int c = blockIdx.y;
    float4 Pr = {1.f, 1.f, 1.f, 1.f};
    float4 Qr = {0.f, 0.f, 0.f, 0.f};
    size_t base = (size_t)c * CHUNK_LEN * NCH4 + j4;
#pragma unroll
    for (int t = 0; t < CHUNK_LEN; ++t) {
        float4 a = alpha[base + (size_t)t * NCH4];
        float4 vv = v[base + (size_t)t * NCH4];
        Pr.x *= a.x; Pr.y *= a.y; Pr.z *= a.z; Pr.w *= a.w;
        Qr.x = a.x * Qr.x + (1.f - a.x) * vv.x;
        Qr.y = a.y * Qr.y + (1.f - a.y) * vv.y;
        Qr.z = a.z * Qr.z + (1.f - a.z) * vv.z;
        Qr.w = a.w * Qr.w + (1.f - a.w) * vv.w;
    }
    P[(size_t)c * NCH4 + j4] = Pr;
    Q[(size_t)c * NCH4 + j4] = Qr;
}

// Phase 2: exclusive prefix over chunks. Scalar per channel: 8192 threads,
// 256 sequential steps (loads are h-independent -> pipelined by unroll).
// Also writes h[0] = h0 (absorbs the memcpy).
__global__ __launch_bounds__(256) void scan_phase2_kernel(
    const float* __restrict__ P, const float* __restrict__ Q,
    const float* __restrict__ h0,   // [NCH]
    float* __restrict__ Hc,         // [CHUNKS][NCH] = h at chunk start
    float* __restrict__ hbase) {    // h[0] region
    const int ch = blockIdx.x * 256 + threadIdx.x;  // 0..NCH-1
    float h = h0[ch];
    hbase[ch] = h;
#pragma unroll 8
    for (int c = 0; c < CHUNKS; ++c) {
        Hc[(size_t)c * NCH + ch] = h;
        h = P[(size_t)c * NCH + ch] * h + Q[(size_t)c * NCH + ch];
    }
}

// Phase 3: replay chunk with correct incoming h; in-place overwrite:
// alpha region -> output, v region -> h[t+1].
__global__ __launch_bounds__(256) void scan_phase3_kernel(
    float4* __restrict__ alpha_out,  // in: alpha[t], out: output[t]
    float4* __restrict__ v_h,        // in: v[t] (at h[t+1] slot), out: h[t+1]
    const float4* __restrict__ Hc) {
    const int j4 = blockIdx.x * 256 + threadIdx.x;
    const int c = blockIdx.y;
    float4 h = Hc[(size_t)c * NCH4 + j4];
    size_t base = (size_t)c * CHUNK_LEN * NCH4 + j4;
#pragma unroll
    for (int t = 0; t < CHUNK_LEN; ++t) {
        float4 a = alpha_out[base + (size_t)t * NCH4];
        float4 vv = v_h[base + (size_t)t * NCH4];
        h.x = a.x * h.x + (1.f - a.x) * vv.x;
        h.y = a.y * h.y + (1.f - a.y) * vv.y;
        h.z = a.z * h.z + (1.f - a.z) * vv.z;
        h.w = a.w * h.w + (1.f - a.w) * vv.w;
        float4 o;
        o.x = h.x * h.x * sigmoidf(h.x);
        o.y = h.y * h.y * sigmoidf(h.y);
        o.z = h.z * h.z * sigmoidf(h.z);
        o.w = h.w * h.w * sigmoidf(h.w);
        alpha_out[base + (size_t)t * NCH4] = o;
        v_h[base + (size_t)t * NCH4] = h;
    }
}

extern "C" void kernel_launch(void* const* d_in, const int* in_sizes, int n_in,
                              void* d_out, int out_size, void* d_ws, size_t ws_size,
                              hipStream_t stream) {
    const float* x  = (const float*)d_in[0];   // [T,B,D]
    const float* h0 = (const float*)d_in[1];   // [B,D]
    const float* Wa = (const float*)d_in[2];   // [D,D]
    const float* ba = (const float*)d_in[3];   // [D]
    const float* Wv = (const float*)d_in[4];   // [D,D]
    const float* bv = (const float*)d_in[5];   // [D]

    float* out = (float*)d_out;                       // output region [T][NCH]
    float* hbase = out + (size_t)T_DIM * NCH;         // h region [T+1][NCH]
    float* alpha = out;                               // temp alpha in output region
    float* vbuf = hbase + NCH;                        // temp v in h[1..T]

    char* ws = (char*)d_ws;
    unsigned short* xb   = (unsigned short*)ws;                 // 32 MB (live
                                                                // only until
                                                                // GEMM ends)
    unsigned short* Wcat = (unsigned short*)(ws + 33554432);    // 4 MB
    // P/Q/Hc (8 MB each) ALIAS the xb region — phase1 runs after the GEMM's
    // last read of xb, so the lifetime split is clean.
    float* P  = (float*)(ws + 0);
    float* Q  = (float*)(ws + 8388608);
    float* Hc = (float*)(ws + 16777216);

    // one-time: allow 72 KiB dynamic LDS for the GEMM
    static bool attr_done = false;
    if (!attr_done) {
        hipFuncSetAttribute(reinterpret_cast<const void*>(gemm_fused_kernel),
                            hipFuncAttributeMaxDynamicSharedMemorySize, 73728);
        attr_done = true;
    }

    // 1. convert all inputs to bf16 (single launch)
    const int nconv = (M_DIM * K_DIM / 4) + (2 * D_DIM * D_DIM / 4);  // 4718592
    convert_all_kernel<<<nconv / 256, 256, 0, stream>>>(
        (const float4*)x, (const float4*)Wa, (const float4*)Wv,
        (ushort4*)xb, (ushort4*)Wcat);

    // 2. fused GEMM: alpha = sigmoid(x Wa^T + ba) -> output region
    //                v     =         x Wv^T + bv  -> h[1..T] region
    gemm_fused_kernel<<<1024, 512, 73728, stream>>>(xb, Wcat, ba, bv, alpha,
                                                    vbuf);

    // 3. chunked scan (phase2 also writes h[0] = h0)
    dim3 sgrid(NCH4 / 256, CHUNKS);
    scan_phase1_kernel<<<sgrid, 256, 0, stream>>>(
        (const float4*)alpha, (const float4*)vbuf, (float4*)P, (float4*)Q);
    scan_phase2_kernel<<<NCH / 256, 256, 0, stream>>>(
        P, Q, h0, Hc, hbase);
    scan_phase3_kernel<<<sgrid, 256, 0, stream>>>(
        (float4*)alpha, (float4*)vbuf, (const float4*)Hc);
}

// Round 5
// 305.256 us; speedup vs baseline: 1.0918x; 1.0918x over previous
//
#include <hip/hip_runtime.h>
#include <hip/hip_bf16.h>

// Problem constants
#define T_DIM 2048
#define B_DIM 8
#define D_DIM 1024
#define M_DIM (T_DIM * B_DIM)     // 16384
#define K_DIM D_DIM               // 1024
#define NW_DIM (2 * D_DIM)        // 2048 combined GEMM cols (alpha | v)
#define NCH (B_DIM * D_DIM)       // 8192 channels
#define NCH4 (NCH / 4)            // 2048 packed-u32x4 channels
#define CHUNKS 64
#define CHUNK_LEN 32              // 64*32 = 2048 = T

typedef __attribute__((ext_vector_type(8))) short bf16x8;
typedef __attribute__((ext_vector_type(4))) float f32x4;

__device__ __forceinline__ unsigned short bf16_rne(float f) {
    unsigned u = __float_as_uint(f);
    unsigned r = u + 0x7fffu + ((u >> 16) & 1u);
    return (unsigned short)(r >> 16);
}

__device__ __forceinline__ float sigmoidf(float z) {
    return 1.0f / (1.0f + __expf(-z));
}

// packed (alpha,v): low u16 = alpha fixed-point /65535 (quant err 7.6e-6,
// negligible in the h-recurrence); high u16 = v bf16 (decode = 1 AND).
__device__ __forceinline__ void decode_av(unsigned u, float& a, float& v) {
    a = (float)(u & 0xffffu) * (1.0f / 65535.f);
    v = __uint_as_float(u & 0xffff0000u);
}

__device__ __forceinline__ void load_lds16(const void* g, void* l) {
    __builtin_amdgcn_global_load_lds(
        (const __attribute__((address_space(1))) void*)g,
        (__attribute__((address_space(3))) void*)l,
        16, 0, 0);
}

// ---------------- fused input conversion: x, Wa, Wv -> bf16 ----------------
__global__ __launch_bounds__(256) void convert_all_kernel(
    const float4* __restrict__ x,
    const float4* __restrict__ Wa,
    const float4* __restrict__ Wv,
    ushort4* __restrict__ xb,
    ushort4* __restrict__ Wcat) {
    const int nx4 = M_DIM * K_DIM / 4;       // 4194304
    const int half4 = D_DIM * D_DIM / 4;     // 262144
    int i = blockIdx.x * 256 + threadIdx.x;
    float4 f;
    ushort4* __restrict__ dst;
    int di;
    if (i < nx4) {
        f = x[i];
        dst = xb;
        di = i;
    } else {
        int j = i - nx4;
        f = (j < half4) ? Wa[j] : Wv[j - half4];
        dst = Wcat;
        di = j;
    }
    ushort4 o;
    o.x = bf16_rne(f.x);
    o.y = bf16_rne(f.y);
    o.z = bf16_rne(f.z);
    o.w = bf16_rne(f.w);
    dst[di] = o;
}

// ---------------- fused bf16 MFMA GEMM, 128x256 tile, 2 blocks/CU --------
// Compute loop unchanged from R3 (clean A/B). Epilogue now writes the
// PACKED av buffer: element e = m*1024+n is a u32 at av[2e]/av[2e+1]
// (ushort view): alpha block writes u16-fixedpoint sigmoid at 2e, v block
// writes bf16 at 2e+1. Write traffic 128 -> 64 MB.
//  - wave tile 64x64 (acc=64 regs) => 4 waves/SIMD (__launch_bounds__(512,4));
//    ring-3 of BK=32 buffers (72 KiB) => 2 blocks/CU. 1024 blocks, bijective
//    XCD swizzle. Depth-2 prefetch; steady vmcnt(3); ONE barrier per K-tile.
//  - LDS XOR swizzle (verified 0 conflicts); inverse perm on global source.
// Known remaining bottleneck (R3 counters): LDS-read BW (A halves read 4x,
// B quarters 2x per K-tile). Fix = 128x64-wave m201 schedule; deferred.
__global__ __launch_bounds__(512, 4) void gemm_fused_kernel(
    const unsigned short* __restrict__ A,
    const unsigned short* __restrict__ W,
    const float* __restrict__ ba,
    const float* __restrict__ bv,
    unsigned short* __restrict__ av) {
    extern __shared__ __attribute__((aligned(16))) char smem[];  // 3*24576

    const int tid = threadIdx.x;
    const int lane = tid & 63;
    const int w = tid >> 6;          // wave 0..7
    const int wm = w >> 2;           // wave row (0..1) -> 64 rows each
    const int wn = w & 3;            // wave col (0..3) -> 64 cols each
    const int quad = lane >> 4;      // 0..3
    const int l16 = lane & 15;

    const int bid = blockIdx.x;
    const int swz = (bid & 7) * 128 + (bid >> 3);
    const int bx = swz & 7;          // N tile (0..7)
    const int by = swz >> 3;         // M tile (0..127)
    const int bm = by * 128;
    const int bn = bx * 256;         // col in the 2048-wide space

    const int vsw = (((l16 & 1) << 2) | quad) ^ (l16 >> 1);
    const int rdA = wm * 4096 + (l16 >> 1) * 128 + vsw * 16;  // + i*1024
    const int rdB = wn * 4096 + (l16 >> 1) * 128 + vsw * 16;  // + j*1024

    const int hl = lane >> 3;            // 0..7
    const int vp = (lane & 7) ^ hl;
    const int qsrc = vp & 3;
    const int rb = (vp >> 2) & 1;
    const int rA  = 16 * w + 2 * hl + rb;        // A tile row 0..127
    const int rB0 = 32 * w + 2 * hl + rb;        // B tile row (grp 2w)
    const int rB1 = rB0 + 16;                    // B tile row (grp 2w+1)
    const char* Ab = (const char*)A;
    const char* Wb = (const char*)W;
    const size_t offA  = (size_t)(bm + rA ) * 2048 + (size_t)qsrc * 16;
    const size_t offB0 = (size_t)(bn + rB0) * 2048 + (size_t)qsrc * 16;
    const size_t offB1 = (size_t)(bn + rB1) * 2048 + (size_t)qsrc * 16;
    const int ldsA  = w * 1024;          // wave-uniform dests
    const int ldsB0 = (2 * w) * 1024;
    const int ldsB1 = (2 * w + 1) * 1024;

    f32x4 acc[4][4];
    {
        f32x4 zero = {0.f, 0.f, 0.f, 0.f};
#pragma unroll
        for (int i = 0; i < 4; ++i)
#pragma unroll
            for (int j = 0; j < 4; ++j) acc[i][j] = zero;
    }

    auto stage = [&](int buf, int t) {
        char* bA = smem + buf * 24576;
        char* bB = bA + 8192;
        const size_t ko = (size_t)t * 64;
        load_lds16(Ab + offA + ko, bA + ldsA);
        load_lds16(Wb + offB0 + ko, bB + ldsB0);
        load_lds16(Wb + offB1 + ko, bB + ldsB1);
    };

    auto tile_step = [&](int buf, int nbuf, int tn, bool do_stage, int vm,
                         bool bar) {
        const char* bA = smem + buf * 24576;
        const char* bB = bA + 8192;
        bf16x8 af[4], bfr[4];
#pragma unroll
        for (int i = 0; i < 4; ++i)
            af[i] = *(const bf16x8*)(bA + rdA + i * 1024);
#pragma unroll
        for (int j = 0; j < 4; ++j)
            bfr[j] = *(const bf16x8*)(bB + rdB + j * 1024);
        if (do_stage) stage(nbuf, tn);
        asm volatile("s_waitcnt lgkmcnt(0)" ::: "memory");
        __builtin_amdgcn_sched_barrier(0);
        __builtin_amdgcn_s_setprio(1);
#pragma unroll
        for (int i = 0; i < 4; ++i)
#pragma unroll
            for (int j = 0; j < 4; ++j)
                acc[i][j] = __builtin_amdgcn_mfma_f32_16x16x32_bf16(
                    af[i], bfr[j], acc[i][j], 0, 0, 0);
        __builtin_amdgcn_s_setprio(0);
        if (vm == 3) asm volatile("s_waitcnt vmcnt(3)" ::: "memory");
        else if (vm == 0) asm volatile("s_waitcnt vmcnt(0)" ::: "memory");
        if (bar) __builtin_amdgcn_s_barrier();
    };

    stage(0, 0);
    stage(1, 1);
    asm volatile("s_waitcnt vmcnt(3)" ::: "memory");
    __builtin_amdgcn_s_barrier();

    for (int it = 0; it < 10; ++it) {
        const int t = it * 3;
        tile_step(0, 2, t + 2, true, 3, true);
        tile_step(1, 0, t + 3, true, 3, true);
        tile_step(2, 1, t + 4, true, 3, true);
    }
    tile_step(0, 0, 0, false, 0, true);    // tile 30; drain tile 31's loads
    tile_step(1, 0, 0, false, -1, false);  // tile 31; no wait/barrier

    // epilogue: C/D layout col = lane&15, row = quad*4 + reg.
    // bn multiples of 256 -> tile entirely alpha or v (block-uniform).
    // alpha -> u16 fixed-point at ushort index 2e; v -> bf16 at 2e+1.
    const bool is_alpha = (bn < D_DIM);
    const float* __restrict__ bias = is_alpha ? ba : bv;
    const int nb = bn - (is_alpha ? 0 : D_DIM);
    const int sel = is_alpha ? 0 : 1;
#pragma unroll
    for (int j = 0; j < 4; ++j) {
        const int n = nb + wn * 64 + j * 16 + l16;
        const float bias_n = bias[n];
#pragma unroll
        for (int i = 0; i < 4; ++i) {
            const int m0 = bm + wm * 64 + i * 16 + quad * 4;
#pragma unroll
            for (int r = 0; r < 4; ++r) {
                float val = acc[i][j][r] + bias_n;
                unsigned short s;
                if (is_alpha)
                    s = (unsigned short)(sigmoidf(val) * 65535.f + 0.5f);
                else
                    s = bf16_rne(val);
                av[((size_t)(m0 + r) * D_DIM + n) * 2 + sel] = s;
            }
        }
    }
}

// ---------------- chunked parallel scan ----------------
// h_t = a_t*h_{t-1} + (1-a_t)*v_t  == affine h_out = P*h_in + Q per chunk.
// R4 A/B evidence: streamer occupancy is NOT the limiter (~2.5 TB/s at both
// 8 and 32 waves/CU) -> optimize BYTES. av is packed 4 B/element; CHUNKS
// reverted to 64 (R4's 256-step phase2 was a ~20 us regression).

// Phase 1: per (chunk, channel4) compute chunk composition (P,Q).
__global__ __launch_bounds__(256) void scan_phase1_kernel(
    const uint4* __restrict__ av,   // [T][NCH4] packed (alpha,v)
    float4* __restrict__ P,         // [CHUNKS][NCH4]
    float4* __restrict__ Q) {
    const int j4 = blockIdx.x * 256 + threadIdx.x;  // 0..NCH4-1
    const int c = blockIdx.y;
    float4 Pr = {1.f, 1.f, 1.f, 1.f};
    float4 Qr = {0.f, 0.f, 0.f, 0.f};
    size_t base = (size_t)c * CHUNK_LEN * NCH4 + j4;
#pragma unroll 4
    for (int t = 0; t < CHUNK_LEN; ++t) {
        uint4 u = av[base + (size_t)t * NCH4];
        float a0, v0, a1, v1, a2, v2, a3, v3;
        decode_av(u.x, a0, v0);
        decode_av(u.y, a1, v1);
        decode_av(u.z, a2, v2);
        decode_av(u.w, a3, v3);
        Pr.x *= a0; Pr.y *= a1; Pr.z *= a2; Pr.w *= a3;
        Qr.x = a0 * Qr.x + (1.f - a0) * v0;
        Qr.y = a1 * Qr.y + (1.f - a1) * v1;
        Qr.z = a2 * Qr.z + (1.f - a2) * v2;
        Qr.w = a3 * Qr.w + (1.f - a3) * v3;
    }
    P[(size_t)c * NCH4 + j4] = Pr;
    Q[(size_t)c * NCH4 + j4] = Qr;
}

// Phase 2: exclusive prefix over chunks. Scalar per channel: 8192 threads,
// 64 sequential steps. Also writes h[0] = h0 (absorbs the memcpy).
__global__ __launch_bounds__(256) void scan_phase2_kernel(
    const float* __restrict__ P, const float* __restrict__ Q,
    const float* __restrict__ h0,   // [NCH]
    float* __restrict__ Hc,         // [CHUNKS][NCH] = h at chunk start
    float* __restrict__ hbase) {    // h[0] region
    const int ch = blockIdx.x * 256 + threadIdx.x;  // 0..NCH-1
    float h = h0[ch];
    hbase[ch] = h;
#pragma unroll 8
    for (int c = 0; c < CHUNKS; ++c) {
        Hc[(size_t)c * NCH + ch] = h;
        h = P[(size_t)c * NCH + ch] * h + Q[(size_t)c * NCH + ch];
    }
}

// Phase 3: replay chunk with correct incoming h. Reads packed av IN PLACE
// and overwrites each element with the f32 output (same 4-byte slot, same
// thread, read-before-write => race-free). h[t+1] goes to the h region.
// Stores typed uint4 through the same pointer as the loads (no TBAA risk).
__global__ __launch_bounds__(256) void scan_phase3_kernel(
    uint4* __restrict__ av_out,     // in: packed (a,v); out: output f32
    float4* __restrict__ hout,      // h region base (h[0] written by p2)
    const float4* __restrict__ Hc) {
    const int j4 = blockIdx.x * 256 + threadIdx.x;
    const int c = blockIdx.y;
    float4 h = Hc[(size_t)c * NCH4 + j4];
    size_t base = (size_t)c * CHUNK_LEN * NCH4 + j4;
#pragma unroll 4
    for (int t = 0; t < CHUNK_LEN; ++t) {
        uint4 u = av_out[base + (size_t)t * NCH4];
        float a0, v0, a1, v1, a2, v2, a3, v3;
        decode_av(u.x, a0, v0);
        decode_av(u.y, a1, v1);
        decode_av(u.z, a2, v2);
        decode_av(u.w, a3, v3);
        h.x = a0 * h.x + (1.f - a0) * v0;
        h.y = a1 * h.y + (1.f - a1) * v1;
        h.z = a2 * h.z + (1.f - a2) * v2;
        h.w = a3 * h.w + (1.f - a3) * v3;
        uint4 o;
        o.x = __float_as_uint(h.x * h.x * sigmoidf(h.x));
        o.y = __float_as_uint(h.y * h.y * sigmoidf(h.y));
        o.z = __float_as_uint(h.z * h.z * sigmoidf(h.z));
        o.w = __float_as_uint(h.w * h.w * sigmoidf(h.w));
        av_out[base + (size_t)t * NCH4] = o;
        hout[((size_t)c * CHUNK_LEN + t + 1) * NCH4 + j4] = h;
    }
}

extern "C" void kernel_launch(void* const* d_in, const int* in_sizes, int n_in,
                              void* d_out, int out_size, void* d_ws, size_t ws_size,
                              hipStream_t stream) {
    const float* x  = (const float*)d_in[0];   // [T,B,D]
    const float* h0 = (const float*)d_in[1];   // [B,D]
    const float* Wa = (const float*)d_in[2];   // [D,D]
    const float* ba = (const float*)d_in[3];   // [D]
    const float* Wv = (const float*)d_in[4];   // [D,D]
    const float* bv = (const float*)d_in[5];   // [D]

    float* out = (float*)d_out;                // output region [T][NCH]
    float* hbase = out + (size_t)T_DIM * NCH;  // h region [T+1][NCH]
    // packed (alpha u16, v bf16) lives IN the out region (4 B/element,
    // same element stride as the f32 output that replaces it in phase 3).
    unsigned short* av = (unsigned short*)out;

    char* ws = (char*)d_ws;
    unsigned short* xb   = (unsigned short*)ws;                      // 32 MB
    unsigned short* Wcat = (unsigned short*)(ws + 33554432);         // 4 MB
    float* P  = (float*)(ws + 37748736);                             // 2 MB
    float* Q  = (float*)(ws + 39845888);                             // 2 MB
    float* Hc = (float*)(ws + 41943040);                             // 2 MB

    // one-time: allow 72 KiB dynamic LDS for the GEMM
    static bool attr_done = false;
    if (!attr_done) {
        hipFuncSetAttribute(reinterpret_cast<const void*>(gemm_fused_kernel),
                            hipFuncAttributeMaxDynamicSharedMemorySize, 73728);
        attr_done = true;
    }

    // 1. convert all inputs to bf16 (single launch)
    const int nconv = (M_DIM * K_DIM / 4) + (2 * D_DIM * D_DIM / 4);  // 4718592
    convert_all_kernel<<<nconv / 256, 256, 0, stream>>>(
        (const float4*)x, (const float4*)Wa, (const float4*)Wv,
        (ushort4*)xb, (ushort4*)Wcat);

    // 2. fused GEMM -> packed av (alpha = sigmoid(x Wa^T + ba) as u16,
    //                             v     =         x Wv^T + bv  as bf16)
    gemm_fused_kernel<<<1024, 512, 73728, stream>>>(xb, Wcat, ba, bv, av);

    // 3. chunked scan (phase2 also writes h[0] = h0)
    dim3 sgrid(NCH4 / 256, CHUNKS);
    scan_phase1_kernel<<<sgrid, 256, 0, stream>>>(
        (const uint4*)out, (float4*)P, (float4*)Q);
    scan_phase2_kernel<<<NCH / 256, 256, 0, stream>>>(
        P, Q, h0, Hc, hbase);
    scan_phase3_kernel<<<sgrid, 256, 0, stream>>>(
        (uint4*)out, (float4*)hbase, (const float4*)Hc);
}